// Round 3
// baseline (32.848 us; speedup 1.0000x reference)
//
#include <hip/hip_runtime.h>
#include <hip/hip_fp16.h>

#define BATCH  1024
#define NVARS  2048
#define N_OUT  4096
#define SC     16                 // batch columns per slice
#define NSLICE (BATCH / SC)       // 64
#define CHUNK  512                // outputs per block
#define NCHUNK (N_OUT / CHUNK)    // 8
#define NLEAF  16

__device__ __forceinline__ __half2 u2h2(unsigned u) {
    union { unsigned u; __half2 h; } c; c.u = u; return c.h;
}
__device__ __forceinline__ unsigned h22u(__half2 h) {
    union { unsigned u; __half2 h; } c; c.h = h; return c.u;
}

// ---------------- flatten: build per-output leaf table ----------------
// T[i*16 + n] = int2{ byteoff = row*32, scbits = half2(s, c) }  so leaf = s*x[row]+c
__global__ void flatten_kernel(const int2* __restrict__ idx0,
                               const int2* __restrict__ idx1,
                               const int2* __restrict__ idx2,
                               const int2* __restrict__ idx3,
                               int2* __restrict__ T)
{
    int i = blockIdx.x * blockDim.x + threadIdx.x;
    if (i >= N_OUT) return;
    int2 p3 = idx3[i];
    int n = 0;
    #pragma unroll
    for (int t = 0; t < 2; ++t) {
        int2 p2 = idx2[t ? p3.y : p3.x];
        #pragma unroll
        for (int u = 0; u < 2; ++u) {
            int2 p1 = idx1[u ? p2.y : p2.x];
            #pragma unroll
            for (int v = 0; v < 2; ++v) {
                int2 p0 = idx0[v ? p1.y : p1.x];
                #pragma unroll
                for (int e = 0; e < 2; ++e) {
                    int k = e ? p0.y : p0.x;
                    int byteoff; float s, c;
                    if (k < 2) { byteoff = 0; s = 0.0f; c = (float)k; }
                    else {
                        byteoff = ((k - 2) >> 1) * 32;   // row * (16 cols * 2B)
                        if (k & 1) { s = -1.0f; c = 1.0f; }
                        else       { s =  1.0f; c = 0.0f; }
                    }
                    __half2 sc = __halves2half2(__float2half(s), __float2half(c));
                    int2 ent; ent.x = byteoff; ent.y = (int)h22u(sc);
                    T[(size_t)i * NLEAF + n] = ent;
                    ++n;
                }
            }
        }
    }
}

// ---------------- main: LDS-staged fused evaluation ----------------
__global__ __launch_bounds__(256) void knowledge_main(
    const float* __restrict__ x,
    const int2* __restrict__ T,
    float* __restrict__ out)
{
    __shared__ unsigned xs[NVARS * 8];   // 64 KB: row r = 16 fp16 cols at byte r*32

    const int bx  = blockIdx.x;
    const int s   = bx & (NSLICE - 1);   // slice index (same-slice blocks share XCD)
    const int ch  = bx >> 6;             // output chunk
    const int tid = threadIdx.x;

    // ---- stage x slice (2048 rows x 16 cols) as fp16, b128 LDS writes ----
    const float4* x4 = (const float4*)x;
    #pragma unroll
    for (int it = 0; it < 16; ++it) {
        int f = it * 256 + tid;          // [0, 4096): (row, 16B-half)
        int r = f >> 1, q = f & 1;
        float4 a = x4[(size_t)r * (BATCH / 4) + s * 4 + q * 2];
        float4 b = x4[(size_t)r * (BATCH / 4) + s * 4 + q * 2 + 1];
        uint4 w;
        w.x = h22u(__floats2half2_rn(a.x, a.y));
        w.y = h22u(__floats2half2_rn(a.z, a.w));
        w.z = h22u(__floats2half2_rn(b.x, b.y));
        w.w = h22u(__floats2half2_rn(b.z, b.w));
        *reinterpret_cast<uint4*>(reinterpret_cast<char*>(xs) + r * 32 + q * 16) = w;
    }
    __syncthreads();

    #pragma unroll
    for (int t = 0; t < 2; ++t) {
        const int i = ch * CHUNK + t * 256 + tid;
        const int4* Tp = (const int4*)(T + (size_t)i * NLEAF);

        float2 accf[8];                  // final accumulator in f32
        #pragma unroll
        for (int k = 0; k < 8; ++k) accf[k] = make_float2(0.f, 0.f);

        #pragma unroll
        for (int a3 = 0; a3 < 2; ++a3) {             // SumLayer (top)
            __half2 prod2[8];
            #pragma unroll
            for (int a2 = 0; a2 < 2; ++a2) {         // ProductLayer
                __half2 sum1[8];
                #pragma unroll
                for (int a1 = 0; a1 < 2; ++a1) {     // SumLayer
                    const int m = a3 * 4 + a2 * 2 + a1;   // pair index
                    int4 tt = Tp[m];                 // leaves 2m, 2m+1
                    const char* base = (const char*)xs;
                    uint4 A0 = *(const uint4*)(base + tt.x);
                    uint4 A1 = *(const uint4*)(base + tt.x + 16);
                    uint4 B0 = *(const uint4*)(base + tt.z);
                    uint4 B1 = *(const uint4*)(base + tt.z + 16);
                    __half2 scA = u2h2((unsigned)tt.y);
                    __half2 scB = u2h2((unsigned)tt.w);
                    __half2 sA = __half2half2(__low2half(scA));
                    __half2 cA = __half2half2(__high2half(scA));
                    __half2 sB = __half2half2(__low2half(scB));
                    __half2 cB = __half2half2(__high2half(scB));
                    unsigned aw[8] = {A0.x, A0.y, A0.z, A0.w, A1.x, A1.y, A1.z, A1.w};
                    unsigned bw[8] = {B0.x, B0.y, B0.z, B0.w, B1.x, B1.y, B1.z, B1.w};
                    #pragma unroll
                    for (int k = 0; k < 8; ++k) {
                        __half2 va = __hfma2(u2h2(aw[k]), sA, cA);
                        __half2 vb = __hfma2(u2h2(bw[k]), sB, cB);
                        __half2 p  = __hmul2(va, vb);          // ProductLayer leaf pair
                        if (a1 == 0) sum1[k] = p;
                        else         sum1[k] = __hadd2(sum1[k], p);  // SumLayer
                    }
                }
                #pragma unroll
                for (int k = 0; k < 8; ++k) {
                    if (a2 == 0) prod2[k] = sum1[k];
                    else         prod2[k] = __hmul2(prod2[k], sum1[k]);  // ProductLayer
                }
            }
            #pragma unroll
            for (int k = 0; k < 8; ++k) {            // top sum in f32
                float2 pf = __half22float2(prod2[k]);
                accf[k].x += pf.x; accf[k].y += pf.y;
            }
        }

        float* dst = out + (size_t)i * BATCH + s * SC;
        #pragma unroll
        for (int k = 0; k < 4; ++k) {
            float4 o = make_float4(accf[2*k].x, accf[2*k].y,
                                   accf[2*k+1].x, accf[2*k+1].y);
            reinterpret_cast<float4*>(dst)[k] = o;
        }
    }
}

// ---------------- fallback (round-1 kernel) if ws too small ----------------
__device__ __forceinline__ float Hval(int k, const float* __restrict__ x, int b) {
    if (k < 2) return (float)k;
    float v = x[((k - 2) >> 1) * BATCH + b];
    return (k & 1) ? 1.0f - v : v;
}

__global__ __launch_bounds__(256) void knowledge_fused_kernel(
    const float* __restrict__ x,
    const int2* __restrict__ idx0,
    const int2* __restrict__ idx1,
    const int2* __restrict__ idx2,
    const int2* __restrict__ idx3,
    float* __restrict__ out)
{
    const int i = blockIdx.x;
    const int b = blockIdx.y * blockDim.x + threadIdx.x;
    const int2 p3 = idx3[i];
    float acc3 = 0.0f;
    #pragma unroll
    for (int t = 0; t < 2; ++t) {
        const int2 p2 = idx2[t ? p3.y : p3.x];
        float prod2 = 1.0f;
        #pragma unroll
        for (int u = 0; u < 2; ++u) {
            const int2 p1 = idx1[u ? p2.y : p2.x];
            float sum1 = 0.0f;
            #pragma unroll
            for (int v = 0; v < 2; ++v) {
                const int2 p0 = idx0[v ? p1.y : p1.x];
                sum1 += Hval(p0.x, x, b) * Hval(p0.y, x, b);
            }
            prod2 *= sum1;
        }
        acc3 += prod2;
    }
    out[(size_t)i * BATCH + b] = acc3;
}

extern "C" void kernel_launch(void* const* d_in, const int* in_sizes, int n_in,
                              void* d_out, int out_size, void* d_ws, size_t ws_size,
                              hipStream_t stream) {
    const float* x    = (const float*)d_in[0];
    const int2*  idx0 = (const int2*)d_in[1];
    const int2*  idx1 = (const int2*)d_in[2];
    const int2*  idx2 = (const int2*)d_in[3];
    const int2*  idx3 = (const int2*)d_in[4];
    float* out = (float*)d_out;

    const size_t t_bytes = (size_t)N_OUT * NLEAF * sizeof(int2);  // 512 KB
    if (ws_size >= t_bytes) {
        int2* T = (int2*)d_ws;
        flatten_kernel<<<(N_OUT + 255) / 256, 256, 0, stream>>>(idx0, idx1, idx2, idx3, T);
        knowledge_main<<<NSLICE * NCHUNK, 256, 0, stream>>>(x, T, out);
    } else {
        dim3 grid(N_OUT, BATCH / 256);
        knowledge_fused_kernel<<<grid, 256, 0, stream>>>(x, idx0, idx1, idx2, idx3, out);
    }
}